// Round 7
// baseline (285.250 us; speedup 1.0000x reference)
//
#include <hip/hip_runtime.h>
#include <math.h>

#define BB 8
#define C 64
#define H 128
#define W 128
#define KO 18   // offset conv out channels (2*3*3)
#define NG 8    // groups
#define CPG 8   // channels per group
#define KK 9    // kernel taps
#define HW (H * W)
#define NCO 96  // padded co for MFMA conv (64 atten + 18 offset + 14 pad)
#define KTOT 576

typedef __bf16 bf16x8 __attribute__((ext_vector_type(8)));
typedef float f32x4 __attribute__((ext_vector_type(4)));
typedef unsigned int uint4v __attribute__((ext_vector_type(4)));

static __device__ __forceinline__ unsigned short f2bf(float f) {
    union { float f; unsigned u; } v; v.f = f;
    unsigned r = v.u + 0x7FFFu + ((v.u >> 16) & 1u);   // RNE
    return (unsigned short)(r >> 16);
}

static __device__ __forceinline__ bf16x8 load_bf8(const unsigned short* p) {
    uint4v u = *(const uint4v*)p;
    return __builtin_bit_cast(bf16x8, u);
}

static __device__ __forceinline__ float bflo(unsigned u) {
    union { unsigned u; float f; } v; v.u = u << 16; return v.f;
}
static __device__ __forceinline__ float bfhi(unsigned u) {
    union { unsigned u; float f; } v; v.u = u & 0xFFFF0000u; return v.f;
}

// ---------------------------------------------------------------------------
// Prep A: x [B][C][H][W] fp32 -> x_cl [B][H][W][C] bf16 (channels-last).
// ---------------------------------------------------------------------------
__global__ __launch_bounds__(256)
void xcl_prep_kernel(const float* __restrict__ x, unsigned short* __restrict__ xcl)
{
    const int lane = threadIdx.x & 63;
    const int cg = threadIdx.x >> 6;          // 0..3
    const size_t P = (size_t)blockIdx.x * 64 + lane;   // global pixel id
    const int b = (int)(P >> 14);             // HW = 16384
    const int hw = (int)(P & 16383);

    union { unsigned short s[16]; uint4v v[2]; } u;
    const float* xp = x + ((size_t)b * C + cg * 16) * HW + hw;
#pragma unroll
    for (int i = 0; i < 16; i++)
        u.s[i] = f2bf(xp[i * HW]);

    uint4v* dst = (uint4v*)(xcl + P * 64 + cg * 16);
    dst[0] = u.v[0];
    dst[1] = u.v[1];
}

// ---------------------------------------------------------------------------
// Prep B: weights -> wT[96][576] bf16, k = tap*64 + ci.
// ---------------------------------------------------------------------------
__global__ __launch_bounds__(256)
void wt_prep_kernel(const float* __restrict__ convw,
                    const float* __restrict__ offw,
                    unsigned short* __restrict__ wT)
{
    const int i = blockIdx.x * 256 + threadIdx.x;
    if (i >= NCO * KTOT) return;
    const int k = i % KTOT;
    const int co = i / KTOT;
    const int t = k >> 6;
    const int ci = k & 63;
    float v = 0.f;
    if (co < 64)       v = convw[((size_t)co * C + ci) * KK + t];
    else if (co < 82)  v = offw[((size_t)(co - 64) * C + ci) * KK + t];
    wT[i] = f2bf(v);
}

// ---------------------------------------------------------------------------
// Fused conv via MFMA implicit GEMM + in-block softmax over W.
// Block = TWO rows (h0, h0+1) of one batch; 4 waves; wave q covers cols
// [32q, 32q+32) on both rows as 4 N-tiles (nt = row*2 + coltile).
// Per K-step: 4 B-loads + 6 A-loads -> 24 MFMA (2x better reuse than 2-nt).
// ---------------------------------------------------------------------------
__global__ __launch_bounds__(256)
void conv_mfma_kernel(const unsigned short* __restrict__ xcl,
                      const unsigned short* __restrict__ wT,
                      const float* __restrict__ offb,
                      const float* __restrict__ prelu_a,
                      float* __restrict__ ws_offset,   // [B][18][H][W]
                      float* __restrict__ ws_atten)    // [B][64][H][W] softmax
{
    __shared__ float smax[4][2][64];
    __shared__ float ssum[4][2][64];

    const int lane = threadIdx.x & 63;
    const int q = __builtin_amdgcn_readfirstlane(threadIdx.x >> 6);  // wave 0..3
    const int m = lane & 15;
    const int qq = lane >> 4;
    const int hp = blockIdx.x & 63;
    const int b = blockIdx.x >> 6;
    const int h0 = hp * 2;

    f32x4 acc[4][6];
#pragma unroll
    for (int nt = 0; nt < 4; nt++)
#pragma unroll
        for (int mt = 0; mt < 6; mt++)
            acc[nt][mt] = (f32x4){0.f, 0.f, 0.f, 0.f};

    const unsigned short* wp[6];
#pragma unroll
    for (int mt = 0; mt < 6; mt++)
        wp[mt] = wT + (size_t)(mt * 16 + m) * KTOT + qq * 8;

    const int col0 = q * 32 + m;

#pragma unroll
    for (int t = 0; t < KK; t++) {
        const int dy = t / 3 - 1;
        const int dx = t % 3 - 1;
#pragma unroll
        for (int half = 0; half < 2; half++) {
            const int ks = t * 64 + half * 32;
            bf16x8 bfr[4];
#pragma unroll
            for (int nt = 0; nt < 4; nt++) {
                const int y = h0 + (nt >> 1) + dy;
                const int xx = col0 + (nt & 1) * 16 + dx;
                const bool ok = (y >= 0) && (y < H) && (xx >= 0) && (xx < W);
                bf16x8 v = {};
                if (ok)
                    v = load_bf8(xcl + (((size_t)(b * H + y) * W + xx) * 64
                                        + half * 32 + qq * 8));
                bfr[nt] = v;
            }
#pragma unroll
            for (int mt = 0; mt < 6; mt++) {
                const bf16x8 afr = load_bf8(wp[mt] + ks);
#pragma unroll
                for (int nt = 0; nt < 4; nt++)
                    acc[nt][mt] = __builtin_amdgcn_mfma_f32_16x16x32_bf16(
                        afr, bfr[nt], acc[nt][mt], 0, 0, 0);
            }
        }
    }

    // ---- offsets (mt 4,5): bias + PReLU, store ----
    const float a = prelu_a[0];
#pragma unroll
    for (int nt = 0; nt < 4; nt++) {
        const int wrow = h0 + (nt >> 1);
        const int wcol = col0 + (nt & 1) * 16;
#pragma unroll
        for (int r = 0; r < 4; r++) {
            const int j = qq * 4 + r;
            float v = acc[nt][4][r] + offb[j];
            v = (v >= 0.f) ? v : a * v;
            ws_offset[((size_t)(b * KO + j)) * HW + wrow * W + wcol] = v;
        }
#pragma unroll
        for (int r = 0; r < 4; r++) {
            const int j = 16 + qq * 4 + r;
            if (j < KO) {
                float v = acc[nt][5][r] + offb[j];
                v = (v >= 0.f) ? v : a * v;
                ws_offset[((size_t)(b * KO + j)) * HW + wrow * W + wcol] = v;
            }
        }
    }

    // ---- fused softmax over each 128-px row for co<64 (mt 0..3) ----
    // phase 1: per-row max
    float pm[2][4][4];
#pragma unroll
    for (int rr = 0; rr < 2; rr++)
#pragma unroll
        for (int mt = 0; mt < 4; mt++)
#pragma unroll
            for (int r = 0; r < 4; r++)
                pm[rr][mt][r] = fmaxf(acc[rr * 2][mt][r], acc[rr * 2 + 1][mt][r]);
#pragma unroll
    for (int off = 1; off < 16; off <<= 1)
#pragma unroll
        for (int rr = 0; rr < 2; rr++)
#pragma unroll
            for (int mt = 0; mt < 4; mt++)
#pragma unroll
                for (int r = 0; r < 4; r++)
                    pm[rr][mt][r] = fmaxf(pm[rr][mt][r],
                                          __shfl_xor(pm[rr][mt][r], off, 64));
    if (m == 0) {
#pragma unroll
        for (int rr = 0; rr < 2; rr++)
#pragma unroll
            for (int mt = 0; mt < 4; mt++)
#pragma unroll
                for (int r = 0; r < 4; r++)
                    smax[q][rr][mt * 16 + qq * 4 + r] = pm[rr][mt][r];
    }
    __syncthreads();

    float gm[2][4][4];
#pragma unroll
    for (int rr = 0; rr < 2; rr++)
#pragma unroll
        for (int mt = 0; mt < 4; mt++)
#pragma unroll
            for (int r = 0; r < 4; r++) {
                const int co = mt * 16 + qq * 4 + r;
                gm[rr][mt][r] = fmaxf(fmaxf(smax[0][rr][co], smax[1][rr][co]),
                                      fmaxf(smax[2][rr][co], smax[3][rr][co]));
            }
    // phase 2: exp + per-row sum
    float ps[2][4][4];
#pragma unroll
    for (int rr = 0; rr < 2; rr++)
#pragma unroll
        for (int mt = 0; mt < 4; mt++)
#pragma unroll
            for (int r = 0; r < 4; r++) {
                acc[rr * 2][mt][r] = __expf(acc[rr * 2][mt][r] - gm[rr][mt][r]);
                acc[rr * 2 + 1][mt][r] = __expf(acc[rr * 2 + 1][mt][r] - gm[rr][mt][r]);
                ps[rr][mt][r] = acc[rr * 2][mt][r] + acc[rr * 2 + 1][mt][r];
            }
#pragma unroll
    for (int off = 1; off < 16; off <<= 1)
#pragma unroll
        for (int rr = 0; rr < 2; rr++)
#pragma unroll
            for (int mt = 0; mt < 4; mt++)
#pragma unroll
                for (int r = 0; r < 4; r++)
                    ps[rr][mt][r] += __shfl_xor(ps[rr][mt][r], off, 64);
    if (m == 0) {
#pragma unroll
        for (int rr = 0; rr < 2; rr++)
#pragma unroll
            for (int mt = 0; mt < 4; mt++)
#pragma unroll
                for (int r = 0; r < 4; r++)
                    ssum[q][rr][mt * 16 + qq * 4 + r] = ps[rr][mt][r];
    }
    __syncthreads();

#pragma unroll
    for (int rr = 0; rr < 2; rr++)
#pragma unroll
        for (int mt = 0; mt < 4; mt++)
#pragma unroll
            for (int r = 0; r < 4; r++) {
                const int co = mt * 16 + qq * 4 + r;
                const float rinv = 1.f / (ssum[0][rr][co] + ssum[1][rr][co]
                                          + ssum[2][rr][co] + ssum[3][rr][co]);
                float* op = ws_atten + ((size_t)(b * 64 + co)) * HW
                            + (h0 + rr) * W;
                op[col0] = acc[rr * 2][mt][r] * rinv;
                op[col0 + 16] = acc[rr * 2 + 1][mt][r] * rinv;
            }
}

// ---------------------------------------------------------------------------
// Deformable conv (groups=8) + bias, then out = atten*feat + x.
// Thread = (pixel, quarter): 2 groups, 16 accumulators. Grid = 2048 blocks
// (8 blocks/CU -> up to 32 waves/CU). XCD swizzle on b.
// ---------------------------------------------------------------------------
__global__ __launch_bounds__(256, 8)
void deform_kernel(const float* __restrict__ x,
                   const unsigned short* __restrict__ xcl, // [B][H][W][64] bf16
                   const float* __restrict__ dw,        // [64][8][3][3]
                   const float* __restrict__ db,        // [64]
                   const float* __restrict__ ws_offset, // [B][18][H][W]
                   const float* __restrict__ ws_atten,  // [B][64][H][W]
                   float* __restrict__ out)             // [B][64][H][W]
{
    __shared__ float wlds[9 * 512];   // [k][g][il][ol]

    for (int i = threadIdx.x; i < 9 * 512; i += 256) {
        int ol = i & 7;
        int il = (i >> 3) & 7;
        int g  = (i >> 6) & 7;
        int k  = i >> 9;
        wlds[i] = dw[((g * 8 + ol) * 8 + il) * 9 + k];
    }
    __syncthreads();

    const int b = blockIdx.x & 7;                    // XCD-aware swizzle
    const int h = (blockIdx.x >> 3) & 127;           // row
    const int qp = blockIdx.x >> 10;                 // 0..1
    const int w = threadIdx.x & 127;
    const int quarter = qp * 2 + (threadIdx.x >> 7); // 0..3 (wave-uniform)
    const int g0 = quarter * 2;                      // first group
    const int co0 = quarter * 16;                    // first out channel

    const unsigned short* xclb = xcl + (size_t)b * HW * 64;
    const float* offp = ws_offset + (size_t)b * KO * HW + h * W + w;

    // prefetch all 18 offset values (independent loads)
    float dyv[9], dxv[9];
#pragma unroll
    for (int k = 0; k < KK; k++) {
        dyv[k] = offp[(2 * k) * HW];
        dxv[k] = offp[(2 * k + 1) * HW];
    }

    float acc[16];
#pragma unroll
    for (int i = 0; i < 16; i++) acc[i] = 0.f;

#pragma unroll
    for (int k = 0; k < KK; k++) {
        const int ky = k / 3;
        const int kx = k - ky * 3;
        const float ys = (float)(h - 1 + ky) + dyv[k];
        const float xs = (float)(w - 1 + kx) + dxv[k];
        const float y0f = floorf(ys), x0f = floorf(xs);
        const int y0 = (int)y0f, x0 = (int)x0f;
        const float fy = ys - y0f, fx = xs - x0f;
        float w00 = (1.f - fy) * (1.f - fx);
        float w01 = (1.f - fy) * fx;
        float w10 = fy * (1.f - fx);
        float w11 = fy * fx;
        const bool vy0 = (y0 >= 0) & (y0 < H);
        const bool vy1 = (y0 + 1 >= 0) & (y0 + 1 < H);
        const bool vx0 = (x0 >= 0) & (x0 < W);
        const bool vx1 = (x0 + 1 >= 0) & (x0 + 1 < W);
        w00 = (vy0 && vx0) ? w00 : 0.f;
        w01 = (vy0 && vx1) ? w01 : 0.f;
        w10 = (vy1 && vx0) ? w10 : 0.f;
        w11 = (vy1 && vx1) ? w11 : 0.f;
        const int yc0 = min(max(y0, 0), H - 1);
        const int yc1 = min(max(y0 + 1, 0), H - 1);
        const int xc0 = min(max(x0, 0), W - 1);
        const int xc1 = min(max(x0 + 1, 0), W - 1);
        const unsigned short* p00 = xclb + (size_t)(yc0 * W + xc0) * 64 + co0;
        const unsigned short* p01 = xclb + (size_t)(yc0 * W + xc1) * 64 + co0;
        const unsigned short* p10 = xclb + (size_t)(yc1 * W + xc0) * 64 + co0;
        const unsigned short* p11 = xclb + (size_t)(yc1 * W + xc1) * 64 + co0;

        const float* wk = wlds + k * 512 + g0 * 64;
#pragma unroll
        for (int g = 0; g < 2; g++) {
            const uint4v c00 = *(const uint4v*)(p00 + g * 8);
            const uint4v c01 = *(const uint4v*)(p01 + g * 8);
            const uint4v c10 = *(const uint4v*)(p10 + g * 8);
            const uint4v c11 = *(const uint4v*)(p11 + g * 8);
            float p[8];
#pragma unroll
            for (int i = 0; i < 4; i++) {
                p[2 * i] = w00 * bflo(c00[i]) + w01 * bflo(c01[i])
                         + w10 * bflo(c10[i]) + w11 * bflo(c11[i]);
                p[2 * i + 1] = w00 * bfhi(c00[i]) + w01 * bfhi(c01[i])
                             + w10 * bfhi(c10[i]) + w11 * bfhi(c11[i]);
            }
            const float* wg = wk + g * 64;
#pragma unroll
            for (int il = 0; il < CPG; il++)
#pragma unroll
                for (int ol = 0; ol < CPG; ol++)
                    acc[g * CPG + ol] = fmaf(p[il], wg[il * 8 + ol],
                                             acc[g * CPG + ol]);
        }
    }

    const float* attp = ws_atten + ((size_t)b * C + co0) * HW + h * W + w;
    const float* xr = x + ((size_t)b * C + co0) * HW + h * W + w;
    float* op = out + ((size_t)b * C + co0) * HW + h * W + w;
#pragma unroll
    for (int j = 0; j < 16; j++) {
        const float f = acc[j] + db[co0 + j];
        op[j * HW] = attp[j * HW] * f + xr[j * HW];
    }
}

// ---------------------------------------------------------------------------
extern "C" void kernel_launch(void* const* d_in, const int* in_sizes, int n_in,
                              void* d_out, int out_size, void* d_ws, size_t ws_size,
                              hipStream_t stream) {
    const float* x        = (const float*)d_in[0];
    const float* offset_w = (const float*)d_in[1];
    const float* offset_b = (const float*)d_in[2];
    const float* prelu_a  = (const float*)d_in[3];
    const float* deconv_w = (const float*)d_in[4];
    const float* deconv_b = (const float*)d_in[5];
    const float* conv_w   = (const float*)d_in[6];
    float* out = (float*)d_out;

    float* ws_offset = (float*)d_ws;                            // B*18*HW f32
    float* ws_atten  = ws_offset + (size_t)BB * KO * HW;        // B*64*HW f32
    unsigned short* xcl = (unsigned short*)(ws_atten + (size_t)BB * C * HW);
    unsigned short* wT  = xcl + (size_t)BB * HW * C;            // 96*576 bf16

    xcl_prep_kernel<<<dim3((BB * HW) / 64), dim3(256), 0, stream>>>(x, xcl);
    wt_prep_kernel<<<dim3((NCO * KTOT + 255) / 256), dim3(256), 0, stream>>>(
        conv_w, offset_w, wT);

    conv_mfma_kernel<<<dim3(BB * H / 2), dim3(256), 0, stream>>>(
        xcl, wT, offset_b, prelu_a, ws_offset, ws_atten);

    deform_kernel<<<dim3(BB * H * 2), dim3(256), 0, stream>>>(
        x, xcl, deconv_w, deconv_b, ws_offset, ws_atten, out);
}

// Round 8
// 235.247 us; speedup vs baseline: 1.2126x; 1.2126x over previous
//
#include <hip/hip_runtime.h>
#include <math.h>

#define BB 8
#define C 64
#define H 128
#define W 128
#define KO 18   // offset conv out channels (2*3*3)
#define NG 8    // groups
#define CPG 8   // channels per group
#define KK 9    // kernel taps
#define HW (H * W)
#define NCO 96  // padded co for MFMA conv (64 atten + 18 offset + 14 pad)
#define KTOT 576
#define AROW 72 // LDS row stride (elements) for staged A: 64 + 8 pad

typedef __bf16 bf16x8 __attribute__((ext_vector_type(8)));
typedef float f32x4 __attribute__((ext_vector_type(4)));
typedef unsigned int uint4v __attribute__((ext_vector_type(4)));

static __device__ __forceinline__ unsigned short f2bf(float f) {
    union { float f; unsigned u; } v; v.f = f;
    unsigned r = v.u + 0x7FFFu + ((v.u >> 16) & 1u);   // RNE
    return (unsigned short)(r >> 16);
}

static __device__ __forceinline__ bf16x8 load_bf8(const unsigned short* p) {
    uint4v u = *(const uint4v*)p;
    return __builtin_bit_cast(bf16x8, u);
}

static __device__ __forceinline__ float bflo(unsigned u) {
    union { unsigned u; float f; } v; v.u = u << 16; return v.f;
}
static __device__ __forceinline__ float bfhi(unsigned u) {
    union { unsigned u; float f; } v; v.u = u & 0xFFFF0000u; return v.f;
}

// ---------------------------------------------------------------------------
// Prep A: x [B][C][H][W] fp32 -> x_cl [B][H][W][C] bf16 (channels-last).
// ---------------------------------------------------------------------------
__global__ __launch_bounds__(256)
void xcl_prep_kernel(const float* __restrict__ x, unsigned short* __restrict__ xcl)
{
    const int lane = threadIdx.x & 63;
    const int cg = threadIdx.x >> 6;          // 0..3
    const size_t P = (size_t)blockIdx.x * 64 + lane;   // global pixel id
    const int b = (int)(P >> 14);             // HW = 16384
    const int hw = (int)(P & 16383);

    union { unsigned short s[16]; uint4v v[2]; } u;
    const float* xp = x + ((size_t)b * C + cg * 16) * HW + hw;
#pragma unroll
    for (int i = 0; i < 16; i++)
        u.s[i] = f2bf(xp[i * HW]);

    uint4v* dst = (uint4v*)(xcl + P * 64 + cg * 16);
    dst[0] = u.v[0];
    dst[1] = u.v[1];
}

// ---------------------------------------------------------------------------
// Prep B: weights -> wT[96][576] bf16, k = tap*64 + ci.
// ---------------------------------------------------------------------------
__global__ __launch_bounds__(256)
void wt_prep_kernel(const float* __restrict__ convw,
                    const float* __restrict__ offw,
                    unsigned short* __restrict__ wT)
{
    const int i = blockIdx.x * 256 + threadIdx.x;
    if (i >= NCO * KTOT) return;
    const int k = i % KTOT;
    const int co = i / KTOT;
    const int t = k >> 6;
    const int ci = k & 63;
    float v = 0.f;
    if (co < 64)       v = convw[((size_t)co * C + ci) * KK + t];
    else if (co < 82)  v = offw[((size_t)(co - 64) * C + ci) * KK + t];
    wT[i] = f2bf(v);
}

// ---------------------------------------------------------------------------
// Fused conv via MFMA implicit GEMM + in-block softmax over W.
// Block = TWO rows (h0, h0+1); 4 waves; wave q covers cols [32q, 32q+32)
// on both rows as 4 N-tiles. Per tap: the 96x64 bf16 weight slab is staged
// into LDS once (shared by all 4 waves; A-reads = ds_read_b128, 2-way-free),
// B-fragments are loaded to registers BEFORE the stage barriers.
// ---------------------------------------------------------------------------
__global__ __launch_bounds__(256)
void conv_mfma_kernel(const unsigned short* __restrict__ xcl,
                      const unsigned short* __restrict__ wT,
                      const float* __restrict__ offb,
                      const float* __restrict__ prelu_a,
                      float* __restrict__ ws_offset,   // [B][18][H][W]
                      float* __restrict__ ws_atten)    // [B][64][H][W] softmax
{
    __shared__ unsigned short aw[NCO * AROW];   // 13.8 KB staged weights
    __shared__ float smax[4][2][64];
    __shared__ float ssum[4][2][64];

    const int lane = threadIdx.x & 63;
    const int q = __builtin_amdgcn_readfirstlane(threadIdx.x >> 6);  // wave 0..3
    const int m = lane & 15;
    const int qq = lane >> 4;
    const int hp = blockIdx.x & 63;
    const int b = blockIdx.x >> 6;
    const int h0 = hp * 2;

    f32x4 acc[4][6];
#pragma unroll
    for (int nt = 0; nt < 4; nt++)
#pragma unroll
        for (int mt = 0; mt < 6; mt++)
            acc[nt][mt] = (f32x4){0.f, 0.f, 0.f, 0.f};

    const int col0 = q * 32 + m;

#pragma unroll
    for (int t = 0; t < KK; t++) {
        const int dy = t / 3 - 1;
        const int dx = t % 3 - 1;

        // ---- B-fragments for this tap (VMEM, overlaps staging below) ----
        bf16x8 bfr[2][4];
#pragma unroll
        for (int half = 0; half < 2; half++)
#pragma unroll
            for (int nt = 0; nt < 4; nt++) {
                const int y = h0 + (nt >> 1) + dy;
                const int xx = col0 + (nt & 1) * 16 + dx;
                const bool ok = (y >= 0) && (y < H) && (xx >= 0) && (xx < W);
                bf16x8 v = {};
                if (ok)
                    v = load_bf8(xcl + (((size_t)(b * H + y) * W + xx) * 64
                                        + half * 32 + qq * 8));
                bfr[half][nt] = v;
            }

        // ---- stage this tap's 96x64 weight slab into LDS ----
        __syncthreads();   // previous tap's A-reads complete
#pragma unroll
        for (int c = threadIdx.x; c < NCO * 8; c += 256) {
            const int row = c >> 3;
            const int col8 = (c & 7) * 8;
            *(uint4v*)(aw + row * AROW + col8) =
                *(const uint4v*)(wT + (size_t)row * KTOT + t * 64 + col8);
        }
        __syncthreads();

        // ---- MFMA with LDS A-fragments ----
#pragma unroll
        for (int half = 0; half < 2; half++) {
#pragma unroll
            for (int mt = 0; mt < 6; mt++) {
                const bf16x8 afr = load_bf8(
                    aw + (mt * 16 + m) * AROW + half * 32 + qq * 8);
#pragma unroll
                for (int nt = 0; nt < 4; nt++)
                    acc[nt][mt] = __builtin_amdgcn_mfma_f32_16x16x32_bf16(
                        afr, bfr[half][nt], acc[nt][mt], 0, 0, 0);
            }
        }
    }

    // ---- offsets (mt 4,5): bias + PReLU, store ----
    const float a = prelu_a[0];
#pragma unroll
    for (int nt = 0; nt < 4; nt++) {
        const int wrow = h0 + (nt >> 1);
        const int wcol = col0 + (nt & 1) * 16;
#pragma unroll
        for (int r = 0; r < 4; r++) {
            const int j = qq * 4 + r;
            float v = acc[nt][4][r] + offb[j];
            v = (v >= 0.f) ? v : a * v;
            ws_offset[((size_t)(b * KO + j)) * HW + wrow * W + wcol] = v;
        }
#pragma unroll
        for (int r = 0; r < 4; r++) {
            const int j = 16 + qq * 4 + r;
            if (j < KO) {
                float v = acc[nt][5][r] + offb[j];
                v = (v >= 0.f) ? v : a * v;
                ws_offset[((size_t)(b * KO + j)) * HW + wrow * W + wcol] = v;
            }
        }
    }

    // ---- fused softmax over each 128-px row for co<64 (mt 0..3) ----
    float pm[2][4][4];
#pragma unroll
    for (int rr = 0; rr < 2; rr++)
#pragma unroll
        for (int mt = 0; mt < 4; mt++)
#pragma unroll
            for (int r = 0; r < 4; r++)
                pm[rr][mt][r] = fmaxf(acc[rr * 2][mt][r], acc[rr * 2 + 1][mt][r]);
#pragma unroll
    for (int off = 1; off < 16; off <<= 1)
#pragma unroll
        for (int rr = 0; rr < 2; rr++)
#pragma unroll
            for (int mt = 0; mt < 4; mt++)
#pragma unroll
                for (int r = 0; r < 4; r++)
                    pm[rr][mt][r] = fmaxf(pm[rr][mt][r],
                                          __shfl_xor(pm[rr][mt][r], off, 64));
    if (m == 0) {
#pragma unroll
        for (int rr = 0; rr < 2; rr++)
#pragma unroll
            for (int mt = 0; mt < 4; mt++)
#pragma unroll
                for (int r = 0; r < 4; r++)
                    smax[q][rr][mt * 16 + qq * 4 + r] = pm[rr][mt][r];
    }
    __syncthreads();

    float gm[2][4][4];
#pragma unroll
    for (int rr = 0; rr < 2; rr++)
#pragma unroll
        for (int mt = 0; mt < 4; mt++)
#pragma unroll
            for (int r = 0; r < 4; r++) {
                const int co = mt * 16 + qq * 4 + r;
                gm[rr][mt][r] = fmaxf(fmaxf(smax[0][rr][co], smax[1][rr][co]),
                                      fmaxf(smax[2][rr][co], smax[3][rr][co]));
            }
    float ps[2][4][4];
#pragma unroll
    for (int rr = 0; rr < 2; rr++)
#pragma unroll
        for (int mt = 0; mt < 4; mt++)
#pragma unroll
            for (int r = 0; r < 4; r++) {
                acc[rr * 2][mt][r] = __expf(acc[rr * 2][mt][r] - gm[rr][mt][r]);
                acc[rr * 2 + 1][mt][r] = __expf(acc[rr * 2 + 1][mt][r] - gm[rr][mt][r]);
                ps[rr][mt][r] = acc[rr * 2][mt][r] + acc[rr * 2 + 1][mt][r];
            }
#pragma unroll
    for (int off = 1; off < 16; off <<= 1)
#pragma unroll
        for (int rr = 0; rr < 2; rr++)
#pragma unroll
            for (int mt = 0; mt < 4; mt++)
#pragma unroll
                for (int r = 0; r < 4; r++)
                    ps[rr][mt][r] += __shfl_xor(ps[rr][mt][r], off, 64);
    if (m == 0) {
#pragma unroll
        for (int rr = 0; rr < 2; rr++)
#pragma unroll
            for (int mt = 0; mt < 4; mt++)
#pragma unroll
                for (int r = 0; r < 4; r++)
                    ssum[q][rr][mt * 16 + qq * 4 + r] = ps[rr][mt][r];
    }
    __syncthreads();

#pragma unroll
    for (int rr = 0; rr < 2; rr++)
#pragma unroll
        for (int mt = 0; mt < 4; mt++)
#pragma unroll
            for (int r = 0; r < 4; r++) {
                const int co = mt * 16 + qq * 4 + r;
                const float rinv = 1.f / (ssum[0][rr][co] + ssum[1][rr][co]
                                          + ssum[2][rr][co] + ssum[3][rr][co]);
                float* op = ws_atten + ((size_t)(b * 64 + co)) * HW
                            + (h0 + rr) * W;
                op[col0] = acc[rr * 2][mt][r] * rinv;
                op[col0 + 16] = acc[rr * 2 + 1][mt][r] * rinv;
            }
}

// ---------------------------------------------------------------------------
// Deformable conv (groups=8) + bias, then out = atten*feat + x.
// Thread = (pixel, channel-half): 4 groups, 32 accumulators. Block = one
// (b,h) row x 2 halves; grid = 1024 blocks. XCD swizzle on b.  (R6 config —
// best measured; quarter-split regressed.)
// ---------------------------------------------------------------------------
__global__ __launch_bounds__(256)
void deform_kernel(const float* __restrict__ x,
                   const unsigned short* __restrict__ xcl, // [B][H][W][64] bf16
                   const float* __restrict__ dw,        // [64][8][3][3]
                   const float* __restrict__ db,        // [64]
                   const float* __restrict__ ws_offset, // [B][18][H][W]
                   const float* __restrict__ ws_atten,  // [B][64][H][W]
                   float* __restrict__ out)             // [B][64][H][W]
{
    __shared__ float wlds[9 * 512];   // [k][g][il][ol]

    for (int i = threadIdx.x; i < 9 * 512; i += 256) {
        int ol = i & 7;
        int il = (i >> 3) & 7;
        int g  = (i >> 6) & 7;
        int k  = i >> 9;
        wlds[i] = dw[((g * 8 + ol) * 8 + il) * 9 + k];
    }
    __syncthreads();

    const int b = blockIdx.x & 7;                    // XCD-aware swizzle
    const int h = blockIdx.x >> 3;                   // 0..127 row
    const int w = threadIdx.x & 127;
    const int half = threadIdx.x >> 7;               // 0..1 (wave-uniform)
    const int g0 = half * 4;                         // first group
    const int co0 = half * 32;                       // first out channel

    const unsigned short* xclb = xcl + (size_t)b * HW * 64;
    const float* offp = ws_offset + (size_t)b * KO * HW + h * W + w;

    float dyv[9], dxv[9];
#pragma unroll
    for (int k = 0; k < KK; k++) {
        dyv[k] = offp[(2 * k) * HW];
        dxv[k] = offp[(2 * k + 1) * HW];
    }

    float acc[32];
#pragma unroll
    for (int i = 0; i < 32; i++) acc[i] = 0.f;

#pragma unroll
    for (int k = 0; k < KK; k++) {
        const int ky = k / 3;
        const int kx = k - ky * 3;
        const float ys = (float)(h - 1 + ky) + dyv[k];
        const float xs = (float)(w - 1 + kx) + dxv[k];
        const float y0f = floorf(ys), x0f = floorf(xs);
        const int y0 = (int)y0f, x0 = (int)x0f;
        const float fy = ys - y0f, fx = xs - x0f;
        float w00 = (1.f - fy) * (1.f - fx);
        float w01 = (1.f - fy) * fx;
        float w10 = fy * (1.f - fx);
        float w11 = fy * fx;
        const bool vy0 = (y0 >= 0) & (y0 < H);
        const bool vy1 = (y0 + 1 >= 0) & (y0 + 1 < H);
        const bool vx0 = (x0 >= 0) & (x0 < W);
        const bool vx1 = (x0 + 1 >= 0) & (x0 + 1 < W);
        w00 = (vy0 && vx0) ? w00 : 0.f;
        w01 = (vy0 && vx1) ? w01 : 0.f;
        w10 = (vy1 && vx0) ? w10 : 0.f;
        w11 = (vy1 && vx1) ? w11 : 0.f;
        const int yc0 = min(max(y0, 0), H - 1);
        const int yc1 = min(max(y0 + 1, 0), H - 1);
        const int xc0 = min(max(x0, 0), W - 1);
        const int xc1 = min(max(x0 + 1, 0), W - 1);
        const unsigned short* p00 = xclb + (size_t)(yc0 * W + xc0) * 64 + co0;
        const unsigned short* p01 = xclb + (size_t)(yc0 * W + xc1) * 64 + co0;
        const unsigned short* p10 = xclb + (size_t)(yc1 * W + xc0) * 64 + co0;
        const unsigned short* p11 = xclb + (size_t)(yc1 * W + xc1) * 64 + co0;

        const float* wk = wlds + k * 512 + g0 * 64;
#pragma unroll
        for (int g = 0; g < 4; g++) {
            const uint4v c00 = *(const uint4v*)(p00 + g * 8);
            const uint4v c01 = *(const uint4v*)(p01 + g * 8);
            const uint4v c10 = *(const uint4v*)(p10 + g * 8);
            const uint4v c11 = *(const uint4v*)(p11 + g * 8);
            float p[8];
#pragma unroll
            for (int i = 0; i < 4; i++) {
                p[2 * i] = w00 * bflo(c00[i]) + w01 * bflo(c01[i])
                         + w10 * bflo(c10[i]) + w11 * bflo(c11[i]);
                p[2 * i + 1] = w00 * bfhi(c00[i]) + w01 * bfhi(c01[i])
                             + w10 * bfhi(c10[i]) + w11 * bfhi(c11[i]);
            }
            const float* wg = wk + g * 64;
#pragma unroll
            for (int il = 0; il < CPG; il++)
#pragma unroll
                for (int ol = 0; ol < CPG; ol++)
                    acc[g * CPG + ol] = fmaf(p[il], wg[il * 8 + ol],
                                             acc[g * CPG + ol]);
        }
    }

    const float* attp = ws_atten + ((size_t)b * C + co0) * HW + h * W + w;
    const float* xr = x + ((size_t)b * C + co0) * HW + h * W + w;
    float* op = out + ((size_t)b * C + co0) * HW + h * W + w;
#pragma unroll
    for (int j = 0; j < 32; j++) {
        const float f = acc[j] + db[co0 + j];
        op[j * HW] = attp[j * HW] * f + xr[j * HW];
    }
}

// ---------------------------------------------------------------------------
extern "C" void kernel_launch(void* const* d_in, const int* in_sizes, int n_in,
                              void* d_out, int out_size, void* d_ws, size_t ws_size,
                              hipStream_t stream) {
    const float* x        = (const float*)d_in[0];
    const float* offset_w = (const float*)d_in[1];
    const float* offset_b = (const float*)d_in[2];
    const float* prelu_a  = (const float*)d_in[3];
    const float* deconv_w = (const float*)d_in[4];
    const float* deconv_b = (const float*)d_in[5];
    const float* conv_w   = (const float*)d_in[6];
    float* out = (float*)d_out;

    float* ws_offset = (float*)d_ws;                            // B*18*HW f32
    float* ws_atten  = ws_offset + (size_t)BB * KO * HW;        // B*64*HW f32
    unsigned short* xcl = (unsigned short*)(ws_atten + (size_t)BB * C * HW);
    unsigned short* wT  = xcl + (size_t)BB * HW * C;            // 96*576 bf16

    xcl_prep_kernel<<<dim3((BB * HW) / 64), dim3(256), 0, stream>>>(x, xcl);
    wt_prep_kernel<<<dim3((NCO * KTOT + 255) / 256), dim3(256), 0, stream>>>(
        conv_w, offset_w, wT);

    conv_mfma_kernel<<<dim3(BB * H / 2), dim3(256), 0, stream>>>(
        xcl, wT, offset_b, prelu_a, ws_offset, ws_atten);

    deform_kernel<<<dim3(BB * H), dim3(256), 0, stream>>>(
        x, xcl, deconv_w, deconv_b, ws_offset, ws_atten, out);
}

// Round 9
// 194.042 us; speedup vs baseline: 1.4700x; 1.2123x over previous
//
#include <hip/hip_runtime.h>
#include <math.h>

#define BB 8
#define C 64
#define H 128
#define W 128
#define KO 18   // offset conv out channels (2*3*3)
#define NG 8    // groups
#define CPG 8   // channels per group
#define KK 9    // kernel taps
#define HW (H * W)
#define NCO 96  // padded co for MFMA conv (64 atten + 18 offset + 14 pad)
#define KTOT 576
#define AROW 72 // LDS row stride (elements) for staged conv A: 64 + 8 pad
#define PROW 72 // LDS row stride for deform patch P: 64 + 8 pad

typedef __bf16 bf16x8 __attribute__((ext_vector_type(8)));
typedef float f32x4 __attribute__((ext_vector_type(4)));
typedef unsigned int uint4v __attribute__((ext_vector_type(4)));

static __device__ __forceinline__ unsigned short f2bf(float f) {
    union { float f; unsigned u; } v; v.f = f;
    unsigned r = v.u + 0x7FFFu + ((v.u >> 16) & 1u);   // RNE
    return (unsigned short)(r >> 16);
}

static __device__ __forceinline__ bf16x8 load_bf8(const unsigned short* p) {
    uint4v u = *(const uint4v*)p;
    return __builtin_bit_cast(bf16x8, u);
}
static __device__ __forceinline__ bf16x8 lds_bf8(const unsigned short* p) {
    uint4v u = *(const uint4v*)p;
    return __builtin_bit_cast(bf16x8, u);
}

static __device__ __forceinline__ float bflo(unsigned u) {
    union { unsigned u; float f; } v; v.u = u << 16; return v.f;
}
static __device__ __forceinline__ float bfhi(unsigned u) {
    union { unsigned u; float f; } v; v.u = u & 0xFFFF0000u; return v.f;
}

// ---------------------------------------------------------------------------
// Prep A: x [B][C][H][W] fp32 -> x_cl [B][H][W][C] bf16 (channels-last).
// ---------------------------------------------------------------------------
__global__ __launch_bounds__(256)
void xcl_prep_kernel(const float* __restrict__ x, unsigned short* __restrict__ xcl)
{
    const int lane = threadIdx.x & 63;
    const int cg = threadIdx.x >> 6;          // 0..3
    const size_t P = (size_t)blockIdx.x * 64 + lane;   // global pixel id
    const int b = (int)(P >> 14);             // HW = 16384
    const int hw = (int)(P & 16383);

    union { unsigned short s[16]; uint4v v[2]; } u;
    const float* xp = x + ((size_t)b * C + cg * 16) * HW + hw;
#pragma unroll
    for (int i = 0; i < 16; i++)
        u.s[i] = f2bf(xp[i * HW]);

    uint4v* dst = (uint4v*)(xcl + P * 64 + cg * 16);
    dst[0] = u.v[0];
    dst[1] = u.v[1];
}

// ---------------------------------------------------------------------------
// Prep B: conv weights -> wT[96][576] bf16, k = tap*64 + ci.
// ---------------------------------------------------------------------------
__global__ __launch_bounds__(256)
void wt_prep_kernel(const float* __restrict__ convw,
                    const float* __restrict__ offw,
                    unsigned short* __restrict__ wT)
{
    const int i = blockIdx.x * 256 + threadIdx.x;
    if (i >= NCO * KTOT) return;
    const int k = i % KTOT;
    const int co = i / KTOT;
    const int t = k >> 6;
    const int ci = k & 63;
    float v = 0.f;
    if (co < 64)       v = convw[((size_t)co * C + ci) * KK + t];
    else if (co < 82)  v = offw[((size_t)(co - 64) * C + ci) * KK + t];
    wT[i] = f2bf(v);
}

// ---------------------------------------------------------------------------
// Prep C: deform weights -> awg[9][2][32 rows][32 ci] bf16, zero-padded
// block-diagonal: row co = hf*32+row, ci_global = hf*32+ci; nonzero iff same
// 8-channel group.  dw layout: [64][8][3][3].
// ---------------------------------------------------------------------------
__global__ __launch_bounds__(256)
void awg_prep_kernel(const float* __restrict__ dw, unsigned short* __restrict__ awg)
{
    const int i = blockIdx.x * 256 + threadIdx.x;
    if (i >= KK * 2 * 32 * 32) return;
    const int ci = i & 31;
    const int row = (i >> 5) & 31;
    const int hf = (i >> 10) & 1;
    const int t = i >> 11;
    const int co = hf * 32 + row;
    const int cig = hf * 32 + ci;
    float v = 0.f;
    if ((co >> 3) == (cig >> 3))
        v = dw[((size_t)co * CPG + (cig & 7)) * KK + t];
    awg[i] = f2bf(v);
}

// ---------------------------------------------------------------------------
// Fused conv via MFMA implicit GEMM + in-block softmax over W.  (R7 version.)
// ---------------------------------------------------------------------------
__global__ __launch_bounds__(256)
void conv_mfma_kernel(const unsigned short* __restrict__ xcl,
                      const unsigned short* __restrict__ wT,
                      const float* __restrict__ offb,
                      const float* __restrict__ prelu_a,
                      float* __restrict__ ws_offset,   // [B][18][H][W]
                      float* __restrict__ ws_atten)    // [B][64][H][W] softmax
{
    __shared__ unsigned short aw[NCO * AROW];   // 13.8 KB staged weights
    __shared__ float smax[4][2][64];
    __shared__ float ssum[4][2][64];

    const int lane = threadIdx.x & 63;
    const int q = __builtin_amdgcn_readfirstlane(threadIdx.x >> 6);  // wave 0..3
    const int m = lane & 15;
    const int qq = lane >> 4;
    const int hp = blockIdx.x & 63;
    const int b = blockIdx.x >> 6;
    const int h0 = hp * 2;

    f32x4 acc[4][6];
#pragma unroll
    for (int nt = 0; nt < 4; nt++)
#pragma unroll
        for (int mt = 0; mt < 6; mt++)
            acc[nt][mt] = (f32x4){0.f, 0.f, 0.f, 0.f};

    const int col0 = q * 32 + m;

#pragma unroll
    for (int t = 0; t < KK; t++) {
        const int dy = t / 3 - 1;
        const int dx = t % 3 - 1;

        bf16x8 bfr[2][4];
#pragma unroll
        for (int half = 0; half < 2; half++)
#pragma unroll
            for (int nt = 0; nt < 4; nt++) {
                const int y = h0 + (nt >> 1) + dy;
                const int xx = col0 + (nt & 1) * 16 + dx;
                const bool ok = (y >= 0) && (y < H) && (xx >= 0) && (xx < W);
                bf16x8 v = {};
                if (ok)
                    v = load_bf8(xcl + (((size_t)(b * H + y) * W + xx) * 64
                                        + half * 32 + qq * 8));
                bfr[half][nt] = v;
            }

        __syncthreads();
#pragma unroll
        for (int c = threadIdx.x; c < NCO * 8; c += 256) {
            const int row = c >> 3;
            const int col8 = (c & 7) * 8;
            *(uint4v*)(aw + row * AROW + col8) =
                *(const uint4v*)(wT + (size_t)row * KTOT + t * 64 + col8);
        }
        __syncthreads();

#pragma unroll
        for (int half = 0; half < 2; half++) {
#pragma unroll
            for (int mt = 0; mt < 6; mt++) {
                const bf16x8 afr = lds_bf8(
                    aw + (mt * 16 + m) * AROW + half * 32 + qq * 8);
#pragma unroll
                for (int nt = 0; nt < 4; nt++)
                    acc[nt][mt] = __builtin_amdgcn_mfma_f32_16x16x32_bf16(
                        afr, bfr[half][nt], acc[nt][mt], 0, 0, 0);
            }
        }
    }

    const float a = prelu_a[0];
#pragma unroll
    for (int nt = 0; nt < 4; nt++) {
        const int wrow = h0 + (nt >> 1);
        const int wcol = col0 + (nt & 1) * 16;
#pragma unroll
        for (int r = 0; r < 4; r++) {
            const int j = qq * 4 + r;
            float v = acc[nt][4][r] + offb[j];
            v = (v >= 0.f) ? v : a * v;
            ws_offset[((size_t)(b * KO + j)) * HW + wrow * W + wcol] = v;
        }
#pragma unroll
        for (int r = 0; r < 4; r++) {
            const int j = 16 + qq * 4 + r;
            if (j < KO) {
                float v = acc[nt][5][r] + offb[j];
                v = (v >= 0.f) ? v : a * v;
                ws_offset[((size_t)(b * KO + j)) * HW + wrow * W + wcol] = v;
            }
        }
    }

    float pm[2][4][4];
#pragma unroll
    for (int rr = 0; rr < 2; rr++)
#pragma unroll
        for (int mt = 0; mt < 4; mt++)
#pragma unroll
            for (int r = 0; r < 4; r++)
                pm[rr][mt][r] = fmaxf(acc[rr * 2][mt][r], acc[rr * 2 + 1][mt][r]);
#pragma unroll
    for (int off = 1; off < 16; off <<= 1)
#pragma unroll
        for (int rr = 0; rr < 2; rr++)
#pragma unroll
            for (int mt = 0; mt < 4; mt++)
#pragma unroll
                for (int r = 0; r < 4; r++)
                    pm[rr][mt][r] = fmaxf(pm[rr][mt][r],
                                          __shfl_xor(pm[rr][mt][r], off, 64));
    if (m == 0) {
#pragma unroll
        for (int rr = 0; rr < 2; rr++)
#pragma unroll
            for (int mt = 0; mt < 4; mt++)
#pragma unroll
                for (int r = 0; r < 4; r++)
                    smax[q][rr][mt * 16 + qq * 4 + r] = pm[rr][mt][r];
    }
    __syncthreads();

    float gm[2][4][4];
#pragma unroll
    for (int rr = 0; rr < 2; rr++)
#pragma unroll
        for (int mt = 0; mt < 4; mt++)
#pragma unroll
            for (int r = 0; r < 4; r++) {
                const int co = mt * 16 + qq * 4 + r;
                gm[rr][mt][r] = fmaxf(fmaxf(smax[0][rr][co], smax[1][rr][co]),
                                      fmaxf(smax[2][rr][co], smax[3][rr][co]));
            }
    float ps[2][4][4];
#pragma unroll
    for (int rr = 0; rr < 2; rr++)
#pragma unroll
        for (int mt = 0; mt < 4; mt++)
#pragma unroll
            for (int r = 0; r < 4; r++) {
                acc[rr * 2][mt][r] = __expf(acc[rr * 2][mt][r] - gm[rr][mt][r]);
                acc[rr * 2 + 1][mt][r] = __expf(acc[rr * 2 + 1][mt][r] - gm[rr][mt][r]);
                ps[rr][mt][r] = acc[rr * 2][mt][r] + acc[rr * 2 + 1][mt][r];
            }
#pragma unroll
    for (int off = 1; off < 16; off <<= 1)
#pragma unroll
        for (int rr = 0; rr < 2; rr++)
#pragma unroll
            for (int mt = 0; mt < 4; mt++)
#pragma unroll
                for (int r = 0; r < 4; r++)
                    ps[rr][mt][r] += __shfl_xor(ps[rr][mt][r], off, 64);
    if (m == 0) {
#pragma unroll
        for (int rr = 0; rr < 2; rr++)
#pragma unroll
            for (int mt = 0; mt < 4; mt++)
#pragma unroll
                for (int r = 0; r < 4; r++)
                    ssum[q][rr][mt * 16 + qq * 4 + r] = ps[rr][mt][r];
    }
    __syncthreads();

#pragma unroll
    for (int rr = 0; rr < 2; rr++)
#pragma unroll
        for (int mt = 0; mt < 4; mt++)
#pragma unroll
            for (int r = 0; r < 4; r++) {
                const int co = mt * 16 + qq * 4 + r;
                const float rinv = 1.f / (ssum[0][rr][co] + ssum[1][rr][co]
                                          + ssum[2][rr][co] + ssum[3][rr][co]);
                float* op = ws_atten + ((size_t)(b * 64 + co)) * HW
                            + (h0 + rr) * W;
                op[col0] = acc[rr * 2][mt][r] * rinv;
                op[col0 + 16] = acc[rr * 2 + 1][mt][r] * rinv;
            }
}

// ---------------------------------------------------------------------------
// Deformable conv via cooperative gather + MFMA.
// Wave owns a 16-px tile. Per tap: 8 lanes cooperatively fetch each 128 B
// channel record (8 VMEM instrs, ~8 lines each); lane interpolates its
// (2 px x 8 ci) chunk in registers; writes bf16 patch to per-wave LDS slab;
// 4 MFMAs (16x16x32) against block-diag weights awg accumulate all 64 co.
// Epilogue: + bias, atten*feat + x.
// ---------------------------------------------------------------------------
__global__ __launch_bounds__(256)
void deform_mfma_kernel(const float* __restrict__ x,
                        const unsigned short* __restrict__ xcl,
                        const unsigned short* __restrict__ awg, // [9][2][32][32]
                        const float* __restrict__ db,
                        const float* __restrict__ ws_offset,
                        const float* __restrict__ ws_atten,
                        float* __restrict__ out)
{
    __shared__ unsigned short Pl[4 * 16 * PROW];   // per-wave patch slabs

    const int lane = threadIdx.x & 63;
    const int wv = __builtin_amdgcn_readfirstlane(threadIdx.x >> 6); // 0..3

    const int b = blockIdx.x & 7;                    // XCD swizzle
    const int h = (blockIdx.x >> 3) & 127;
    const int halfrow = blockIdx.x >> 10;            // 0..1
    const int w0 = halfrow * 64 + wv * 16;           // tile's first pixel

    const int pA = lane >> 3;          // px 0..7 of tile
    const int pB = pA + 8;             // px 8..15
    const int ch = lane & 7;           // 8-ci chunk

    const unsigned short* xclb = xcl + (size_t)b * HW * 64;
    const float* offbase = ws_offset + (size_t)b * KO * HW + h * W + w0;
    unsigned short* Pw = Pl + wv * 16 * PROW;

    f32x4 acc[4];
#pragma unroll
    for (int i = 0; i < 4; i++) acc[i] = (f32x4){0.f, 0.f, 0.f, 0.f};

#pragma unroll
    for (int t = 0; t < KK; t++) {
        const int ky = t / 3;
        const int kx = t - ky * 3;
        // offsets for this tap, both pixels
        const float dyA = offbase[(2 * t) * HW + pA];
        const float dxA = offbase[(2 * t + 1) * HW + pA];
        const float dyB = offbase[(2 * t) * HW + pB];
        const float dxB = offbase[(2 * t + 1) * HW + pB];

        // corner geometry for pA
        float wa[4], wb[4];
        int oa[4], ob[4];
        {
            const float ys = (float)(h - 1 + ky) + dyA;
            const float xs = (float)(w0 + pA - 1 + kx) + dxA;
            const float y0f = floorf(ys), x0f = floorf(xs);
            const int y0 = (int)y0f, x0 = (int)x0f;
            const float fy = ys - y0f, fx = xs - x0f;
            const bool vy0 = (y0 >= 0) & (y0 < H), vy1 = (y0 + 1 >= 0) & (y0 + 1 < H);
            const bool vx0 = (x0 >= 0) & (x0 < W), vx1 = (x0 + 1 >= 0) & (x0 + 1 < W);
            wa[0] = (vy0 && vx0) ? (1.f - fy) * (1.f - fx) : 0.f;
            wa[1] = (vy0 && vx1) ? (1.f - fy) * fx : 0.f;
            wa[2] = (vy1 && vx0) ? fy * (1.f - fx) : 0.f;
            wa[3] = (vy1 && vx1) ? fy * fx : 0.f;
            const int yc0 = min(max(y0, 0), H - 1), yc1 = min(max(y0 + 1, 0), H - 1);
            const int xc0 = min(max(x0, 0), W - 1), xc1 = min(max(x0 + 1, 0), W - 1);
            oa[0] = (yc0 * W + xc0) * 64; oa[1] = (yc0 * W + xc1) * 64;
            oa[2] = (yc1 * W + xc0) * 64; oa[3] = (yc1 * W + xc1) * 64;
        }
        {
            const float ys = (float)(h - 1 + ky) + dyB;
            const float xs = (float)(w0 + pB - 1 + kx) + dxB;
            const float y0f = floorf(ys), x0f = floorf(xs);
            const int y0 = (int)y0f, x0 = (int)x0f;
            const float fy = ys - y0f, fx = xs - x0f;
            const bool vy0 = (y0 >= 0) & (y0 < H), vy1 = (y0 + 1 >= 0) & (y0 + 1 < H);
            const bool vx0 = (x0 >= 0) & (x0 < W), vx1 = (x0 + 1 >= 0) & (x0 + 1 < W);
            wb[0] = (vy0 && vx0) ? (1.f - fy) * (1.f - fx) : 0.f;
            wb[1] = (vy0 && vx1) ? (1.f - fy) * fx : 0.f;
            wb[2] = (vy1 && vx0) ? fy * (1.f - fx) : 0.f;
            wb[3] = (vy1 && vx1) ? fy * fx : 0.f;
            const int yc0 = min(max(y0, 0), H - 1), yc1 = min(max(y0 + 1, 0), H - 1);
            const int xc0 = min(max(x0, 0), W - 1), xc1 = min(max(x0 + 1, 0), W - 1);
            ob[0] = (yc0 * W + xc0) * 64; ob[1] = (yc0 * W + xc1) * 64;
            ob[2] = (yc1 * W + xc0) * 64; ob[3] = (yc1 * W + xc1) * 64;
        }

        // cooperative corner fetch: lane reads its 16-B chunk of 8 records
        uint4v rA[4], rB[4];
#pragma unroll
        for (int c = 0; c < 4; c++) {
            rA[c] = *(const uint4v*)(xclb + oa[c] + ch * 8);
            rB[c] = *(const uint4v*)(xclb + ob[c] + ch * 8);
        }

        // interpolate 8 ci for each of the 2 px, pack bf16, write to P slab
        {
            unsigned dwo[4];
#pragma unroll
            for (int d = 0; d < 4; d++) {
                const float lo = wa[0] * bflo(rA[0][d]) + wa[1] * bflo(rA[1][d])
                               + wa[2] * bflo(rA[2][d]) + wa[3] * bflo(rA[3][d]);
                const float hi = wa[0] * bfhi(rA[0][d]) + wa[1] * bfhi(rA[1][d])
                               + wa[2] * bfhi(rA[2][d]) + wa[3] * bfhi(rA[3][d]);
                dwo[d] = (unsigned)f2bf(lo) | ((unsigned)f2bf(hi) << 16);
            }
            *(uint4v*)(Pw + pA * PROW + ch * 8) = (uint4v){dwo[0], dwo[1], dwo[2], dwo[3]};
        }
        {
            unsigned dwo[4];
#pragma unroll
            for (int d = 0; d < 4; d++) {
                const float lo = wb[0] * bflo(rB[0][d]) + wb[1] * bflo(rB[1][d])
                               + wb[2] * bflo(rB[2][d]) + wb[3] * bflo(rB[3][d]);
                const float hi = wb[0] * bfhi(rB[0][d]) + wb[1] * bfhi(rB[1][d])
                               + wb[2] * bfhi(rB[2][d]) + wb[3] * bfhi(rB[3][d]);
                dwo[d] = (unsigned)f2bf(lo) | ((unsigned)f2bf(hi) << 16);
            }
            *(uint4v*)(Pw + pB * PROW + ch * 8) = (uint4v){dwo[0], dwo[1], dwo[2], dwo[3]};
        }

        // wave-internal: drain DS writes before cross-lane DS reads
        asm volatile("s_waitcnt lgkmcnt(0)" ::: "memory");

        // MFMA: 2 hf x 2 m-tiles against block-diag weights
        const int m = lane & 15;
        const int qq = lane >> 4;
#pragma unroll
        for (int hf = 0; hf < 2; hf++) {
            const bf16x8 bfr = lds_bf8(Pw + m * PROW + hf * 32 + qq * 8);
#pragma unroll
            for (int mtl = 0; mtl < 2; mtl++) {
                const bf16x8 afr = load_bf8(
                    awg + ((size_t)((t * 2 + hf) * 32 + mtl * 16 + m)) * 32 + qq * 8);
                acc[hf * 2 + mtl] = __builtin_amdgcn_mfma_f32_16x16x32_bf16(
                    afr, bfr, acc[hf * 2 + mtl], 0, 0, 0);
            }
        }
        // DS ops in program order; next tap's writes follow this tap's reads
        asm volatile("s_waitcnt lgkmcnt(0)" ::: "memory");
    }

    // epilogue: D[co = a*16 + qq*4 + r][px = lane&15]
    const int n = lane & 15;
    const int qq = lane >> 4;
    const float* attp = ws_atten + (size_t)b * C * HW + h * W + w0 + n;
    const float* xr = x + (size_t)b * C * HW + h * W + w0 + n;
    float* op = out + (size_t)b * C * HW + h * W + w0 + n;
#pragma unroll
    for (int a = 0; a < 4; a++)
#pragma unroll
        for (int r = 0; r < 4; r++) {
            const int co = a * 16 + qq * 4 + r;
            const float f = acc[a][r] + db[co];
            op[(size_t)co * HW] = attp[(size_t)co * HW] * f + xr[(size_t)co * HW];
        }
}

// ---------------------------------------------------------------------------
extern "C" void kernel_launch(void* const* d_in, const int* in_sizes, int n_in,
                              void* d_out, int out_size, void* d_ws, size_t ws_size,
                              hipStream_t stream) {
    const float* x        = (const float*)d_in[0];
    const float* offset_w = (const float*)d_in[1];
    const float* offset_b = (const float*)d_in[2];
    const float* prelu_a  = (const float*)d_in[3];
    const float* deconv_w = (const float*)d_in[4];
    const float* deconv_b = (const float*)d_in[5];
    const float* conv_w   = (const float*)d_in[6];
    float* out = (float*)d_out;

    float* ws_offset = (float*)d_ws;                            // B*18*HW f32
    float* ws_atten  = ws_offset + (size_t)BB * KO * HW;        // B*64*HW f32
    unsigned short* xcl = (unsigned short*)(ws_atten + (size_t)BB * C * HW);
    unsigned short* wT  = xcl + (size_t)BB * HW * C;            // 96*576 bf16
    unsigned short* awg = wT + (size_t)NCO * KTOT;              // 9*2*32*32 bf16

    xcl_prep_kernel<<<dim3((BB * HW) / 64), dim3(256), 0, stream>>>(x, xcl);
    wt_prep_kernel<<<dim3((NCO * KTOT + 255) / 256), dim3(256), 0, stream>>>(
        conv_w, offset_w, wT);
    awg_prep_kernel<<<dim3((KK * 2 * 32 * 32 + 255) / 256), dim3(256), 0, stream>>>(
        deconv_w, awg);

    conv_mfma_kernel<<<dim3(BB * H / 2), dim3(256), 0, stream>>>(
        xcl, wT, offset_b, prelu_a, ws_offset, ws_atten);

    deform_mfma_kernel<<<dim3(BB * H * 2), dim3(256), 0, stream>>>(
        x, xcl, awg, deconv_b, ws_offset, ws_atten, out);
}